// Round 5
// baseline (11.359 us; speedup 1.0000x reference)
//
#include <hip/hip_runtime.h>

#define BATCH    512
#define L_TOT    569
#define NALLELE  16
#define SEG_LEN  59
#define D_MODEL  256
#define K_CAND   8
#define VOCAB    30
#define COMMON   25
#define NEG_FILL -1000.0f

// 8 threads per (b,allele) pair; thread h handles l = 8h .. 8h+7 (rows 59..63
// are zero pads). One block = 32 pairs = 2 batch rows, x staged in LDS.
// Single __syncthreads() in the whole kernel.
__global__ __launch_bounds__(256) void mhc_pool_kernel(
    const int*   __restrict__ x,      // (512, 569)
    const float* __restrict__ emb,    // (30, 256)
    const float* __restrict__ wpool,  // (8, 59)
    const float* __restrict__ wpred,  // (256,)
    const float* __restrict__ bpred,  // (1,)
    float*       __restrict__ out)    // (512, 32)
{
    __shared__ int   s_x[2 * L_TOT];    // 2 batch rows of tokens
    __shared__ float s_edot[VOCAB];     // <emb[v,:], wpred>
    __shared__ float s_pedot[64];       // <PE[l,:],  wpred>, rows 59..63 = 0
    __shared__ float s_wpT[64][8];      // wpool^T, rows 59..63 = 0

    const int t = threadIdx.x;

    // ---- stage 2 token rows, perfectly coalesced (5 iters/thread)
    {
        const int base = blockIdx.x * (2 * L_TOT);
        for (int idx = t; idx < 2 * L_TOT; idx += 256)
            s_x[idx] = x[base + idx];
    }

    // ---- table build, no intermediate syncs (shuffle-combined partials)
    const float c0 = -0.035977892f;     // -ln(10000)/256
    if (t < 120) {                      // e_dot: 4 threads per emb row, 64 dims each
        const int j = t >> 2, q = t & 3;
        const float4* e = reinterpret_cast<const float4*>(emb + j * D_MODEL + q * 64);
        const float4* w = reinterpret_cast<const float4*>(wpred + q * 64);
        float a0 = 0, a1 = 0, a2 = 0, a3 = 0;
        #pragma unroll
        for (int p = 0; p < 16; ++p) {
            const float4 ev = e[p], wv = w[p];
            a0 = fmaf(ev.x, wv.x, a0);
            a1 = fmaf(ev.y, wv.y, a1);
            a2 = fmaf(ev.z, wv.z, a2);
            a3 = fmaf(ev.w, wv.w, a3);
        }
        float part = (a0 + a1) + (a2 + a3);
        part += __shfl_xor(part, 1);
        part += __shfl_xor(part, 2);
        if (q == 0) s_edot[j] = part;
    } else if (t < 238) {               // pe_dot: 2 threads per PE row, 32 pairs each
        const int tt = t - 120;
        const int j = tt >> 1, q = tt & 1;
        const float pos = (float)j;
        float       dv  = q ? __expf(c0 * 64.0f) : 1.0f;   // freq of pair 32q
        const float r   = __expf(c0 * 2.0f);
        float a0 = 0.0f, a1 = 0.0f;
        #pragma unroll
        for (int p = 0; p < 32; ++p) {
            const float2 wv  = reinterpret_cast<const float2*>(wpred)[32 * q + p];
            const float  ang = pos * dv;
            a0 = fmaf(__sinf(ang), wv.x, a0);
            a1 = fmaf(__cosf(ang), wv.y, a1);
            dv *= r;
        }
        float part = a0 + a1;
        part += __shfl_xor(part, 1);
        if (q == 0) s_pedot[j] = part;
    } else if (t < 243) {               // zero the pe_dot pad rows
        s_pedot[59 + (t - 238)] = 0.0f;
    }
    for (int idx = t; idx < 512; idx += 256) {   // wpool^T, pad rows zero (2 iters)
        const int l = idx >> 3, k = idx & 7;
        s_wpT[l][k] = (l < SEG_LEN) ? wpool[k * SEG_LEN + l] : 0.0f;
    }
    __syncthreads();

    // ---- main: 8 positions per thread, 8 FMA each
    const int  pr = t >> 3;                    // pair within block, 0..31
    const int  h  = t & 7;
    const int  g  = blockIdx.x * 32 + pr;      // global pair id
    const int  i  = g & (NALLELE - 1);
    const int  b  = g >> 4;
    const int* srow = s_x + (pr >> 4) * L_TOT; // local batch row

    float acc[K_CAND] = {0, 0, 0, 0, 0, 0, 0, 0};
    #pragma unroll
    for (int q = 0; q < 8; ++q) {
        const int l   = 8 * h + q;
        // pad rows (l>=59): read a valid dummy token; s_wpT row is 0 -> no effect
        const int off = (l < COMMON) ? l
                      : (l < SEG_LEN) ? (34 * i + l)
                                      : 0;
        const int tok = srow[off];
        const float s = (tok != 0) ? (s_edot[tok] + s_pedot[l]) : 0.0f;
        const float4 wlo = *reinterpret_cast<const float4*>(&s_wpT[l][0]);
        const float4 whi = *reinterpret_cast<const float4*>(&s_wpT[l][4]);
        acc[0] = fmaf(wlo.x, s, acc[0]);
        acc[1] = fmaf(wlo.y, s, acc[1]);
        acc[2] = fmaf(wlo.z, s, acc[2]);
        acc[3] = fmaf(wlo.w, s, acc[3]);
        acc[4] = fmaf(whi.x, s, acc[4]);
        acc[5] = fmaf(whi.y, s, acc[5]);
        acc[6] = fmaf(whi.z, s, acc[6]);
        acc[7] = fmaf(whi.w, s, acc[7]);
    }

    // reduce across the 8 threads of the pair
    #pragma unroll
    for (int k = 0; k < K_CAND; ++k) {
        acc[k] += __shfl_xor(acc[k], 1);
        acc[k] += __shfl_xor(acc[k], 2);
        acc[k] += __shfl_xor(acc[k], 4);
    }

    if (h == 0) {
        float bv = acc[0]; int bk = 0;
        #pragma unroll
        for (int k = 1; k < K_CAND; ++k)
            if (acc[k] > bv) { bv = acc[k]; bk = k; }   // strict >: first-occurrence
        const bool pres = (srow[COMMON + 34 * i] != 0);
        out[b * 32 + i]           = pres ? (bv + bpred[0]) : NEG_FILL;
        out[b * 32 + NALLELE + i] = pres ? (float)bk       : -1.0f;
    }
}

extern "C" void kernel_launch(void* const* d_in, const int* in_sizes, int n_in,
                              void* d_out, int out_size, void* d_ws, size_t ws_size,
                              hipStream_t stream) {
    const int*   x     = (const int*)  d_in[0];
    const float* emb   = (const float*)d_in[1];
    const float* wpool = (const float*)d_in[2];
    const float* wpred = (const float*)d_in[3];
    const float* bpred = (const float*)d_in[4];
    float*       out   = (float*)d_out;

    // 8192 pairs x 8 threads = 65536 threads = 256 blocks (1 per CU)
    mhc_pool_kernel<<<256, 256, 0, stream>>>(x, emb, wpool, wpred, bpred, out);
}

// Round 6
// 11.171 us; speedup vs baseline: 1.0169x; 1.0169x over previous
//
#include <hip/hip_runtime.h>

#define BATCH    512
#define L_TOT    569
#define NALLELE  16
#define SEG_LEN  59
#define D_MODEL  256
#define K_CAND   8
#define VOCAB    30
#define COMMON   25
#define NEG_FILL -1000.0f

// 4 threads per (b,allele) pair; thread h handles l = 15h .. 15h+14 (l=59 is a
// zero pad row in both tables). Single __syncthreads() in the whole kernel.
// All global loads (tokens, bpred, emb, wpred, wpool) issue before the barrier
// so one HBM-latency generation covers everything.
__global__ __launch_bounds__(256) void mhc_pool_kernel(
    const int*   __restrict__ x,      // (512, 569)
    const float* __restrict__ emb,    // (30, 256)
    const float* __restrict__ wpool,  // (8, 59)
    const float* __restrict__ wpred,  // (256,)
    const float* __restrict__ bpred,  // (1,)
    float*       __restrict__ out)    // (512, 32)
{
    __shared__ float s_edot[VOCAB];     // <emb[v,:], wpred>
    __shared__ float s_pedot[60];       // <PE[l,:],  wpred>, [59] = 0
    __shared__ float s_wpT[60][8];      // wpool^T, row 59 = 0

    const int t = threadIdx.x;
    const int h = t & 3;                // position-slice within the pair
    const int g = blockIdx.x * 64 + (t >> 2);   // pair id 0..8191
    const int i = g & (NALLELE - 1);
    const int b = g >> 4;
    const int rowbase = b * L_TOT;

    const float bp = bpred[0];          // hoisted: latency hides under table build

    // ---- issue all token loads FIRST; latency hides under the table build.
    int toks[15];
    #pragma unroll
    for (int q = 0; q < 15; ++q) {
        const int l = 15 * h + q;
        const int addr = (l < COMMON) ? (rowbase + l)
                       : (l < SEG_LEN) ? (rowbase + 34 * i + l)
                                       : rowbase;            // l==59 dummy
        toks[q] = x[addr];
    }
    // presence token (l==25) lives in the h==1 thread's toks[10]; no extra load.

    // ---- table build, no intermediate syncs (shuffle-combined partials).
    const float c0 = -0.035977892f;     // -ln(10000)/256
    if (t < 120) {                      // e_dot: quad (4 threads) per emb row
        const int j = t >> 2, q = t & 3;
        const float4* e = reinterpret_cast<const float4*>(emb + j * D_MODEL + q * 64);
        const float4* w = reinterpret_cast<const float4*>(wpred + q * 64);
        float a0 = 0, a1 = 0, a2 = 0, a3 = 0;
        #pragma unroll
        for (int p = 0; p < 16; ++p) {
            const float4 ev = e[p], wv = w[p];
            a0 = fmaf(ev.x, wv.x, a0);
            a1 = fmaf(ev.y, wv.y, a1);
            a2 = fmaf(ev.z, wv.z, a2);
            a3 = fmaf(ev.w, wv.w, a3);
        }
        float part = (a0 + a1) + (a2 + a3);
        part += __shfl_xor(part, 1);
        part += __shfl_xor(part, 2);
        if (q == 0) s_edot[j] = part;
    } else if (t < 238) {               // pe_dot: 2 threads per PE row
        const int tt = t - 120;
        const int j = tt >> 1, q = tt & 1;
        const float pos = (float)j;
        float       dv  = q ? __expf(c0 * 64.0f) : 1.0f;   // freq of pair 32q
        const float r   = __expf(c0 * 2.0f);
        float a0 = 0.0f, a1 = 0.0f;
        #pragma unroll
        for (int p = 0; p < 32; ++p) {
            const float2 wv  = reinterpret_cast<const float2*>(wpred)[32 * q + p];
            const float  ang = pos * dv;
            a0 = fmaf(__sinf(ang), wv.x, a0);
            a1 = fmaf(__cosf(ang), wv.y, a1);
            dv *= r;
        }
        float part = a0 + a1;
        part += __shfl_xor(part, 1);
        if (q == 0) s_pedot[j] = part;
        if (tt == 116) s_pedot[59] = 0.0f;   // pad
    }
    for (int idx = t; idx < 480; idx += 256) {   // wpool^T + zero pad row
        const int l = idx >> 3, k = idx & 7;
        s_wpT[l][k] = (l < SEG_LEN) ? wpool[k * SEG_LEN + l] : 0.0f;
    }
    __syncthreads();

    // ---- main: 15 positions per thread, 8 FMA each.
    float acc[K_CAND] = {0, 0, 0, 0, 0, 0, 0, 0};
    #pragma unroll
    for (int q = 0; q < 15; ++q) {
        const int   l   = 15 * h + q;
        const int   tok = toks[q];
        const float s   = (tok != 0) ? (s_edot[tok] + s_pedot[l]) : 0.0f;
        const float4 wlo = *reinterpret_cast<const float4*>(&s_wpT[l][0]);
        const float4 whi = *reinterpret_cast<const float4*>(&s_wpT[l][4]);
        acc[0] = fmaf(wlo.x, s, acc[0]);
        acc[1] = fmaf(wlo.y, s, acc[1]);
        acc[2] = fmaf(wlo.z, s, acc[2]);
        acc[3] = fmaf(wlo.w, s, acc[3]);
        acc[4] = fmaf(whi.x, s, acc[4]);
        acc[5] = fmaf(whi.y, s, acc[5]);
        acc[6] = fmaf(whi.z, s, acc[6]);
        acc[7] = fmaf(whi.w, s, acc[7]);
    }

    // reduce across the 4 threads of the pair
    #pragma unroll
    for (int k = 0; k < K_CAND; ++k) {
        acc[k] += __shfl_xor(acc[k], 1);
        acc[k] += __shfl_xor(acc[k], 2);
    }

    const int tokp = __shfl_xor(toks[10], 1);   // h==0 receives h==1's l=25 token

    if (h == 0) {
        float bv = acc[0]; int bk = 0;
        #pragma unroll
        for (int k = 1; k < K_CAND; ++k)
            if (acc[k] > bv) { bv = acc[k]; bk = k; }   // strict >: first-occurrence
        const bool pres = (tokp != 0);
        out[b * 32 + i]           = pres ? (bv + bp)  : NEG_FILL;
        out[b * 32 + NALLELE + i] = pres ? (float)bk  : -1.0f;
    }
}

extern "C" void kernel_launch(void* const* d_in, const int* in_sizes, int n_in,
                              void* d_out, int out_size, void* d_ws, size_t ws_size,
                              hipStream_t stream) {
    const int*   x     = (const int*)  d_in[0];
    const float* emb   = (const float*)d_in[1];
    const float* wpool = (const float*)d_in[2];
    const float* wpred = (const float*)d_in[3];
    const float* bpred = (const float*)d_in[4];
    float*       out   = (float*)d_out;

    // 8192 pairs x 4 threads = 32768 threads = 128 blocks
    mhc_pool_kernel<<<128, 256, 0, stream>>>(x, emb, wpool, wpred, bpred, out);
}